// Round 1
// baseline (568.356 us; speedup 1.0000x reference)
//
#include <hip/hip_runtime.h>
#include <hip/hip_bf16.h>

#define B_  4
#define L_  2048
#define D_  512
#define H_  8
#define HD_ 64
#define M_  (B_ * L_)   // 8192

typedef __bf16 bf16;
typedef __attribute__((ext_vector_type(8))) __bf16 bf16x8;
typedef __attribute__((ext_vector_type(4))) float  f32x4;

__device__ __forceinline__ f32x4 mfma16(bf16x8 a, bf16x8 b, f32x4 c) {
    return __builtin_amdgcn_mfma_f32_16x16x32_bf16(a, b, c, 0, 0, 0);
}

__device__ __forceinline__ bf16x8 cvt8(float4 x0, float4 x1) {
    bf16x8 t;
    t[0] = (bf16)x0.x; t[1] = (bf16)x0.y; t[2] = (bf16)x0.z; t[3] = (bf16)x0.w;
    t[4] = (bf16)x1.x; t[5] = (bf16)x1.y; t[6] = (bf16)x1.z; t[7] = (bf16)x1.w;
    return t;
}

// C[M,N] = relu(X[M,K] @ W[N,K]^T + b[N]);  M=8192, N=K=512.
// OUT_MODE 0: bf16, head layout [B,H,L,HD]
// OUT_MODE 1: bf16, transposed head layout [B,H,HD,L]
// OUT_MODE 2: fp32, row-major [M,N]  (final output)
template<bool IN_BF16, int OUT_MODE>
__global__ __launch_bounds__(256) void proj_kernel(
    const void* __restrict__ Xv, const float* __restrict__ W,
    const float* __restrict__ bias, void* __restrict__ outv)
{
    const int wave = threadIdx.x >> 6;
    const int lane = threadIdx.x & 63;
    const int quad = lane >> 4;
    const int l15  = lane & 15;
    const int m_base = blockIdx.x * 128 + wave * 32;  // wave: 32 rows
    const int n_base = blockIdx.y * 64;               // block: 64 cols

    f32x4 acc[2][4];
#pragma unroll
    for (int mi = 0; mi < 2; mi++)
#pragma unroll
        for (int ni = 0; ni < 4; ni++) acc[mi][ni] = (f32x4){0.f, 0.f, 0.f, 0.f};

    const float* Xf = (const float*)Xv;
    const bf16*  Xb = (const bf16*)Xv;

    for (int k0 = 0; k0 < D_; k0 += 32) {
        const int ka = k0 + quad * 8;
        bf16x8 afrag[2], bfrag[4];
#pragma unroll
        for (int mi = 0; mi < 2; mi++) {
            const int row = m_base + mi * 16 + l15;
            if (IN_BF16) {
                afrag[mi] = *(const bf16x8*)(Xb + (size_t)row * D_ + ka);
            } else {
                const float4* p = (const float4*)(Xf + (size_t)row * D_ + ka);
                afrag[mi] = cvt8(p[0], p[1]);
            }
        }
#pragma unroll
        for (int ni = 0; ni < 4; ni++) {
            const int wrow = n_base + ni * 16 + l15;
            const float4* p = (const float4*)(W + (size_t)wrow * D_ + ka);
            bfrag[ni] = cvt8(p[0], p[1]);
        }
#pragma unroll
        for (int mi = 0; mi < 2; mi++)
#pragma unroll
            for (int ni = 0; ni < 4; ni++)
                acc[mi][ni] = mfma16(afrag[mi], bfrag[ni], acc[mi][ni]);
    }

#pragma unroll
    for (int mi = 0; mi < 2; mi++)
#pragma unroll
        for (int ni = 0; ni < 4; ni++)
#pragma unroll
            for (int r = 0; r < 4; r++) {
                const int row = m_base + mi * 16 + quad * 4 + r;
                const int col = n_base + ni * 16 + l15;
                float v = acc[mi][ni][r] + bias[col];
                v = fmaxf(v, 0.0f);
                if (OUT_MODE == 2) {
                    ((float*)outv)[(size_t)row * D_ + col] = v;
                } else {
                    const int b = row >> 11, l = row & (L_ - 1);
                    const int h = col >> 6,  hd = col & (HD_ - 1);
                    size_t idx;
                    if (OUT_MODE == 0)
                        idx = ((size_t)(b * H_ + h) * L_ + l) * HD_ + hd;
                    else
                        idx = ((size_t)(b * H_ + h) * HD_ + hd) * L_ + l;
                    ((bf16*)outv)[idx] = (bf16)v;
                }
            }
}

// Flash attention. qh, kh: [B,H,L,HD] bf16;  vt: [B,H,HD,L] bf16.
// Output Obuf: [B,L,D] bf16. grid = (L/64, B*H), block = 256 (4 waves).
__global__ __launch_bounds__(256) void attn_kernel(
    const bf16* __restrict__ qh, const bf16* __restrict__ kh,
    const bf16* __restrict__ vt, bf16* __restrict__ Obuf)
{
    const int wave = threadIdx.x >> 6;
    const int lane = threadIdx.x & 63;
    const int quad = lane >> 4;
    const int l15  = lane & 15;
    const int bh   = blockIdx.y;
    const int q_base = blockIdx.x * 64 + wave * 16;

    const bf16* Q = qh + (size_t)bh * L_ * HD_;
    const bf16* K = kh + (size_t)bh * L_ * HD_;
    const bf16* V = vt + (size_t)bh * HD_ * L_;

    __shared__ __align__(16) bf16 Plds[4][16][72];  // +8 pad: b128 reads <=2-way

    // Q fragments, reused across all j-tiles. A[m=l15][k=quad*8+j (+32*ks)]
    bf16x8 qf[2];
#pragma unroll
    for (int ks = 0; ks < 2; ks++)
        qf[ks] = *(const bf16x8*)(Q + (size_t)(q_base + l15) * HD_ + ks * 32 + quad * 8);

    float m_i[4], l_i[4];
    f32x4 o_acc[4];
#pragma unroll
    for (int r = 0; r < 4; r++) { m_i[r] = -1e30f; l_i[r] = 0.0f; }
#pragma unroll
    for (int nb = 0; nb < 4; nb++) o_acc[nb] = (f32x4){0.f, 0.f, 0.f, 0.f};

    const float scale = 0.044194173824159216f;  // 1/sqrt(512)

    for (int j0 = 0; j0 < L_; j0 += 64) {
        // S = Q @ K^T : 16 x 64, C-layout (row=quad*4+r, col=nb*16+l15)
        f32x4 s_acc[4];
#pragma unroll
        for (int nb = 0; nb < 4; nb++) s_acc[nb] = (f32x4){0.f, 0.f, 0.f, 0.f};
#pragma unroll
        for (int ks = 0; ks < 2; ks++)
#pragma unroll
            for (int nb = 0; nb < 4; nb++) {
                bf16x8 kf = *(const bf16x8*)(K + (size_t)(j0 + nb * 16 + l15) * HD_ + ks * 32 + quad * 8);
                s_acc[nb] = mfma16(qf[ks], kf, s_acc[nb]);
            }

        // Online softmax per q-row; row stats reduce across the 16-lane quad group.
#pragma unroll
        for (int r = 0; r < 4; r++) {
            float s0 = s_acc[0][r] * scale, s1 = s_acc[1][r] * scale;
            float s2 = s_acc[2][r] * scale, s3 = s_acc[3][r] * scale;
            float lm = fmaxf(fmaxf(s0, s1), fmaxf(s2, s3));
            lm = fmaxf(lm, __shfl_xor(lm, 1));
            lm = fmaxf(lm, __shfl_xor(lm, 2));
            lm = fmaxf(lm, __shfl_xor(lm, 4));
            lm = fmaxf(lm, __shfl_xor(lm, 8));
            const float mnew  = fmaxf(m_i[r], lm);
            const float alpha = __expf(m_i[r] - mnew);
            m_i[r] = mnew;
            const float e0 = __expf(s0 - mnew), e1 = __expf(s1 - mnew);
            const float e2 = __expf(s2 - mnew), e3 = __expf(s3 - mnew);
            float ls = e0 + e1 + e2 + e3;
            ls += __shfl_xor(ls, 1);
            ls += __shfl_xor(ls, 2);
            ls += __shfl_xor(ls, 4);
            ls += __shfl_xor(ls, 8);
            l_i[r] = l_i[r] * alpha + ls;
#pragma unroll
            for (int nb = 0; nb < 4; nb++) o_acc[nb][r] *= alpha;
            const int prow = quad * 4 + r;
            Plds[wave][prow][0 * 16 + l15] = (bf16)e0;
            Plds[wave][prow][1 * 16 + l15] = (bf16)e1;
            Plds[wave][prow][2 * 16 + l15] = (bf16)e2;
            Plds[wave][prow][3 * 16 + l15] = (bf16)e3;
        }
        // Each wave reads only its own LDS region: in-wave write->read ordering.
        asm volatile("s_waitcnt lgkmcnt(0)" ::: "memory");

        // O += P @ V.  P A-layout read from LDS; V B-frag contiguous from vt.
#pragma unroll
        for (int ks = 0; ks < 2; ks++) {
            bf16x8 pf = *(const bf16x8*)(&Plds[wave][l15][ks * 32 + quad * 8]);
#pragma unroll
            for (int nb = 0; nb < 4; nb++) {
                bf16x8 vf = *(const bf16x8*)(V + (size_t)(nb * 16 + l15) * L_ + j0 + ks * 32 + quad * 8);
                o_acc[nb] = mfma16(pf, vf, o_acc[nb]);
            }
        }
    }

    // Normalize + store to [B, L, D] bf16.
    const int b = bh >> 3, h = bh & 7;
#pragma unroll
    for (int nb = 0; nb < 4; nb++)
#pragma unroll
        for (int r = 0; r < 4; r++) {
            const int row = q_base + quad * 4 + r;
            const int col = nb * 16 + l15;
            const float ov = o_acc[nb][r] / l_i[r];
            Obuf[(size_t)(b * L_ + row) * D_ + h * HD_ + col] = (bf16)ov;
        }
}

extern "C" void kernel_launch(void* const* d_in, const int* in_sizes, int n_in,
                              void* d_out, int out_size, void* d_ws, size_t ws_size,
                              hipStream_t stream)
{
    (void)in_sizes; (void)n_in; (void)out_size; (void)ws_size;
    const float* q  = (const float*)d_in[0];
    const float* k  = (const float*)d_in[1];
    const float* v  = (const float*)d_in[2];
    const float* Wq = (const float*)d_in[3];
    const float* bq = (const float*)d_in[4];
    const float* Wk = (const float*)d_in[5];
    const float* bk = (const float*)d_in[6];
    const float* Wv = (const float*)d_in[7];
    const float* bv = (const float*)d_in[8];
    const float* Wo = (const float*)d_in[9];
    const float* bo = (const float*)d_in[10];
    float* out = (float*)d_out;

    char* ws = (char*)d_ws;
    const size_t SZ = (size_t)8 * 1024 * 1024;  // B*H*L*HD * 2B = 8 MB each
    bf16* qh = (bf16*)(ws);
    bf16* kh = (bf16*)(ws + SZ);
    bf16* vt = (bf16*)(ws + 2 * SZ);
    bf16* Ob = (bf16*)(ws + 3 * SZ);

    dim3 pgrid(M_ / 128, D_ / 64), pblock(256);
    proj_kernel<false, 0><<<pgrid, pblock, 0, stream>>>(q, Wq, bq, qh);
    proj_kernel<false, 0><<<pgrid, pblock, 0, stream>>>(k, Wk, bk, kh);
    proj_kernel<false, 1><<<pgrid, pblock, 0, stream>>>(v, Wv, bv, vt);

    attn_kernel<<<dim3(L_ / 64, B_ * H_), pblock, 0, stream>>>(qh, kh, vt, Ob);

    proj_kernel<true, 2><<<pgrid, pblock, 0, stream>>>(Ob, Wo, bo, out);
}